// Round 8
// baseline (214.192 us; speedup 1.0000x reference)
//
#include <hip/hip_runtime.h>
#include <hip/hip_bf16.h>
#include <stdint.h>

// Problem constants
#define NROWS 4096
#define NCLS  97
#define EMB   768
#define KTOT  49152                 // EMB * 64
#define OUT_ELEMS (NROWS * NCLS)    // 397312
#define E_ELEMS  (NROWS * EMB)      // 3,145,728
#define NK32  (KTOT / 32)           // 1536 k-chunks of 32
#define WT_BYTES ((size_t)NK32 * 128 * 64)   // 12,582,912 (Wt: [kc][c<128][32] f16)

typedef __attribute__((ext_vector_type(4)))  float floatx4;
typedef _Float16 f16x2 __attribute__((ext_vector_type(2)));
typedef _Float16 f16x8 __attribute__((ext_vector_type(8)));

// Pack 8 f32 -> 8 f16 (RNE via scalar casts) as a uint4.
__device__ __forceinline__ uint4 cvt8h(float4 a, float4 b) {
  f16x8 v;
  v[0] = (_Float16)a.x; v[1] = (_Float16)a.y; v[2] = (_Float16)a.z; v[3] = (_Float16)a.w;
  v[4] = (_Float16)b.x; v[5] = (_Float16)b.y; v[6] = (_Float16)b.z; v[7] = (_Float16)b.w;
  return __builtin_bit_cast(uint4, v);
}

// Prep: build Wt (W transposed into MFMA B-fragment order, f16, classes
// padded to 128 with zeros). b1/b2 are consumed in f32 directly.
// Wt 16B-chunk t: eo=t&3 (8-elem octet), c=(t>>2)&127, kc=t>>9:
//   Wt byte addr = kc*8192 + c*64 + eo*16  <-> W[c][kc*32 + eo*8 .. +7]
__global__ void prep(const float* __restrict__ W, uint4* __restrict__ wt)
{
  const int nwt = NK32 * 128 * 4;      // 786,432
  int t = blockIdx.x * blockDim.x + threadIdx.x;
  if (t >= nwt) return;
  int eo = t & 3;
  int c  = (t >> 2) & 127;
  int kc = t >> 9;
  uint4 v = uint4{0u, 0u, 0u, 0u};
  if (c < NCLS) {
    const float4* p = (const float4*)(W + (size_t)c * KTOT + kc * 32 + eo * 8);
    v = cvt8h(p[0], p[1]);
  }
  wt[t] = v;
}

// Fused on-the-fly-A GEMM, R17 = R16 structure, de-risked sync.
// (R16 bench died with "container failed twice" — same infra signature as
// R4 whose identical resubmit passed; but R16 was also the first kernel
// with raw asm-waitcnt barriers, so this resubmit replaces them with plain
// __syncthreads(). Its implicit vmcnt(0) drain is nearly free because the
// staged loads are issued a full window EARLY (T14) — ~600 cyc old at the
// barrier.)
// Theory (R10..R15): MfmaUtil pinned 24-30% across FOUR register-level
// schedules; per SIMD window-pair 3771 cyc = 1086 MFMA + ~650 VALU + ~2100
// DEAD = unhidden per-window global->VGPR latency (compiler won't pipeline
// at source level, guide m133; 2 correlated waves/SIMD can't cover it).
// R17 structure (window = 64 k = 16KB Wt tile shared by all 4 waves,
// dedups the mhalf-pair duplication 28KB->16KB global traffic/block):
//   1) issue next window's stage loads to regs (4 x dwordx4/wave, early)
//   2) 7 x ds_read_b128 fragments + f16 A-build + 28 MFMA
//   3) __syncthreads()  (all waves done reading; staged loads long done)
//   4) ds_write staged regs -> LDS
//   5) __syncthreads()  (writes visible)
// ds_read bank check: lane addr = chalf*4096 + l15*64 + quad*16 -> 16B-slot
// multiplicity 8 = same as contiguous read = minimum (no swizzle needed).
// b1 gather double-buffered one group ahead. f16 path, rt=4, ct3-pad skip,
// KS=16, grid (16,32), 2 blocks/CU kept.
// MFMA 16x16x32 verified triple:
//   A: lane l holds A[m=l&15][k=(l>>4)*8+j]; B: W[c=l&15][k=(l>>4)*8+j]
//   D: lane l, reg r: col(c)=l&15, row(n)=(l>>4)*4+r
__global__ __launch_bounds__(256, 2)
void bilinear_main(const float* __restrict__ b1f,
                   const float* __restrict__ b2f,
                   const char* __restrict__ Wt,
                   const float* __restrict__ biasg,
                   float* __restrict__ P,
                   float* __restrict__ outd,
                   int klen)
{
  const int tid  = threadIdx.x;
  const int w    = tid >> 6;
  const int l    = tid & 63;
  const int l15  = l & 15;
  const int quad = l >> 4;
  const int mhalf = w & 1;
  const int chalf = w >> 1;
  const bool cfull = (chalf == 0);   // chalf=1 waves skip ct==3 (zero pad)
  const int bm = blockIdx.y;
  const int k0 = blockIdx.x * klen;

  __shared__ uint4 sW[1024];          // 16 KiB window buffer

  int nrow[4];
#pragma unroll
  for (int rt = 0; rt < 4; ++rt) nrow[rt] = bm * 128 + mhalf * 64 + rt * 16 + l15;

  const char* wtbase = Wt + (size_t)(k0 >> 5) * 8192;  // block's k-slice
  // Reader fragment slot (uint4 units): slot = kh*512 + c*4 + q,
  // c = chalf*64 + ct*16 + l15, q = quad  ->  rslot + kh*512 + ct*64.
  const int rslot = chalf * 256 + l15 * 4 + quad;

  floatx4 acc[4][4];
#pragma unroll
  for (int rt = 0; rt < 4; ++rt)
#pragma unroll
    for (int ct = 0; ct < 4; ++ct)
      acc[rt][ct] = floatx4{0.f, 0.f, 0.f, 0.f};

  // f16-pair cache of b2[nrow[rt], kb*64 + kh*32 + quad*8 + 2j,2j+1].
  f16x2 b2h[4][2][4];
  float4 b1cur[4], b1nxt[4];
  uint4  wst[4];                      // staged next-window Wt (T14 regs)

#define LOADB2(kbv) do {                                                      \
    _Pragma("unroll")                                                         \
    for (int rt_ = 0; rt_ < 4; ++rt_)                                         \
      _Pragma("unroll")                                                       \
      for (int kh_ = 0; kh_ < 2; ++kh_) {                                     \
        const float* p_ = b2f + (size_t)nrow[rt_] * EMB + (kbv) * 64 +        \
                          kh_ * 32 + quad * 8;                                \
        float4 v0_ = ((const float4*)p_)[0];                                  \
        float4 v1_ = ((const float4*)p_)[1];                                  \
        b2h[rt_][kh_][0][0] = (_Float16)v0_.x; b2h[rt_][kh_][0][1] = (_Float16)v0_.y; \
        b2h[rt_][kh_][1][0] = (_Float16)v0_.z; b2h[rt_][kh_][1][1] = (_Float16)v0_.w; \
        b2h[rt_][kh_][2][0] = (_Float16)v1_.x; b2h[rt_][kh_][2][1] = (_Float16)v1_.y; \
        b2h[rt_][kh_][3][0] = (_Float16)v1_.z; b2h[rt_][kh_][3][1] = (_Float16)v1_.w; \
      }                                                                       \
  } while (0)

  const int nwin = klen >> 6;         // 64-k windows
  const int ngrp = nwin >> 2;         // groups of 4 windows (256 k, one b1v)

  // ---- prologue: stage window 0, b2/b1 for group 0 ----
  {
    const uint4* g0 = (const uint4*)wtbase;
#pragma unroll
    for (int it = 0; it < 4; ++it) wst[it] = g0[it * 256 + tid];
#pragma unroll
    for (int it = 0; it < 4; ++it) sW[it * 256 + tid] = wst[it];
  }
  int cur_kb = k0 >> 12;
  LOADB2(cur_kb);
#pragma unroll
  for (int rt = 0; rt < 4; ++rt)
    b1cur[rt] = *(const float4*)(b1f + (size_t)nrow[rt] * EMB +
                                 cur_kb * 64 + ((k0 >> 6) & 63));
  __syncthreads();

  for (int gp = 0; gp < ngrp; ++gp) {
    const int kap_g = k0 + gp * 256;
    const int kb = kap_g >> 12;
    if (kb != cur_kb) { cur_kb = kb; LOADB2(kb); }   // uniform, rare
    {
      // prefetch next group's b1 gather (hidden under ~4 windows of compute)
      const int h = (gp + 1 < ngrp) ? gp + 1 : gp;
      const int kap_h = k0 + h * 256;
#pragma unroll
      for (int rt = 0; rt < 4; ++rt)
        b1nxt[rt] = *(const float4*)(b1f + (size_t)nrow[rt] * EMB +
                                     (kap_h >> 12) * 64 + ((kap_h >> 6) & 63));
    }

#pragma unroll
    for (int s = 0; s < 4; ++s) {
      const int iw = gp * 4 + s;

      // (1) issue next window's stage loads (consumed after barrier #1)
      if (iw + 1 < nwin) {
        const uint4* gn = (const uint4*)(wtbase + (size_t)(iw + 1) * 16384);
#pragma unroll
        for (int it = 0; it < 4; ++it) wst[it] = gn[it * 256 + tid];
      }

      // (2) fragments from LDS + f16 A-build + MFMA
      uint4 wf[2][4];
#pragma unroll
      for (int kh = 0; kh < 2; ++kh)
#pragma unroll
        for (int ct = 0; ct < 4; ++ct)
          if (ct < 3 || cfull)
            wf[kh][ct] = sW[kh * 512 + ct * 64 + rslot];

      f16x2 sv[4];
#pragma unroll
      for (int rt = 0; rt < 4; ++rt) {
        _Float16 h = (_Float16)((&b1cur[rt].x)[s]);
        sv[rt][0] = h; sv[rt][1] = h;
      }

#pragma unroll
      for (int kh = 0; kh < 2; ++kh)
#pragma unroll
        for (int rt = 0; rt < 4; ++rt) {
          f16x2 p0 = sv[rt] * b2h[rt][kh][0];
          f16x2 p1 = sv[rt] * b2h[rt][kh][1];
          f16x2 p2 = sv[rt] * b2h[rt][kh][2];
          f16x2 p3 = sv[rt] * b2h[rt][kh][3];
          uint4 au;
          au.x = __builtin_bit_cast(uint32_t, p0);
          au.y = __builtin_bit_cast(uint32_t, p1);
          au.z = __builtin_bit_cast(uint32_t, p2);
          au.w = __builtin_bit_cast(uint32_t, p3);
          f16x8 af = __builtin_bit_cast(f16x8, au);
#pragma unroll
          for (int ct = 0; ct < 4; ++ct)
            if (ct < 3 || cfull)
              acc[rt][ct] = __builtin_amdgcn_mfma_f32_16x16x32_f16(
                  af, __builtin_bit_cast(f16x8, wf[kh][ct]),
                  acc[rt][ct], 0, 0, 0);
        }

      // (3) all waves done reading this window
      __syncthreads();

      // (4) write staged regs -> LDS
      if (iw + 1 < nwin) {
#pragma unroll
        for (int it = 0; it < 4; ++it) sW[it * 256 + tid] = wst[it];
      }

      // (5) writes visible to all waves before next window's reads
      __syncthreads();
    }
#pragma unroll
    for (int rt = 0; rt < 4; ++rt) b1cur[rt] = b1nxt[rt];
  }
#undef LOADB2

  // Epilogue. D: col(c)=l15, row(n)=quad*4+r within each 16x16 tile.
  if (P) {
    float* Pb = P + (size_t)blockIdx.x * OUT_ELEMS;   // slice = blockIdx.x
#pragma unroll
    for (int rt = 0; rt < 4; ++rt)
#pragma unroll
      for (int ct = 0; ct < 4; ++ct) {
        const int c = chalf * 64 + ct * 16 + l15;
        if (c < NCLS) {
#pragma unroll
          for (int r = 0; r < 4; ++r) {
            const int row = bm * 128 + mhalf * 64 + rt * 16 + quad * 4 + r;
            Pb[(size_t)row * NCLS + c] = acc[rt][ct][r];
          }
        }
      }
  } else {
#pragma unroll
    for (int rt = 0; rt < 4; ++rt)
#pragma unroll
      for (int ct = 0; ct < 4; ++ct) {
        const int c = chalf * 64 + ct * 16 + l15;
        if (c < NCLS) {
          const float bv = biasg[c];
#pragma unroll
          for (int r = 0; r < 4; ++r) {
            const int row = bm * 128 + mhalf * 64 + rt * 16 + quad * 4 + r;
            outd[(size_t)row * NCLS + c] = acc[rt][ct][r] + bv;
          }
        }
      }
  }
}

// Sum KS partial slices + f32 bias -> f32 output. float4-vectorized.
// KS templated so the accumulation loop fully unrolls (runtime bound left a
// dependent load->add chain, one L2 latency per slice).
template<int KSC>
__global__ void reduce_bias_t(const float* __restrict__ P,
                              const float* __restrict__ biasg,
                              float* __restrict__ out)
{
  int i = blockIdx.x * blockDim.x + threadIdx.x;
  const int n4 = OUT_ELEMS / 4;           // 99328
  if (i >= n4) return;
  int c0 = (i * 4) % NCLS;
  int c1 = c0 + 1 == NCLS ? 0 : c0 + 1;
  int c2 = c1 + 1 == NCLS ? 0 : c1 + 1;
  int c3 = c2 + 1 == NCLS ? 0 : c2 + 1;
  float4 s;
  s.x = biasg[c0]; s.y = biasg[c1]; s.z = biasg[c2]; s.w = biasg[c3];
  const float4* P4 = (const float4*)P;
#pragma unroll
  for (int t = 0; t < KSC; ++t) {
    float4 v = P4[(size_t)t * n4 + i];
    s.x += v.x; s.y += v.y; s.z += v.z; s.w += v.w;
  }
  ((float4*)out)[i] = s;
}

static void launch_reduce(int KS, const float* P, const float* bb, float* out,
                          hipStream_t stream) {
  const int nb = (OUT_ELEMS / 4 + 255) / 256;
  switch (KS) {
    case 16: reduce_bias_t<16><<<nb, 256, 0, stream>>>(P, bb, out); break;
    case 12: reduce_bias_t<12><<<nb, 256, 0, stream>>>(P, bb, out); break;
    case 8:  reduce_bias_t<8><<<nb, 256, 0, stream>>>(P, bb, out);  break;
    case 6:  reduce_bias_t<6><<<nb, 256, 0, stream>>>(P, bb, out);  break;
    case 4:  reduce_bias_t<4><<<nb, 256, 0, stream>>>(P, bb, out);  break;
    case 3:  reduce_bias_t<3><<<nb, 256, 0, stream>>>(P, bb, out);  break;
    case 2:  reduce_bias_t<2><<<nb, 256, 0, stream>>>(P, bb, out);  break;
    default: reduce_bias_t<1><<<nb, 256, 0, stream>>>(P, bb, out);  break;
  }
}

extern "C" void kernel_launch(void* const* d_in, const int* in_sizes, int n_in,
                              void* d_out, int out_size, void* d_ws, size_t ws_size,
                              hipStream_t stream) {
  const float* b1f = (const float*)d_in[0];   // [4096,768] f32
  const float* b2f = (const float*)d_in[1];   // [4096,768] f32
  const float* Wf  = (const float*)d_in[2];   // [97, 49152] f32
  const float* bbf = (const float*)d_in[3];   // [97] f32
  float* out = (float*)d_out;

  const size_t slice = (size_t)OUT_ELEMS * 4;     // 1,589,248
  // klen = KTOT/KS must be a multiple of 512 -> KS divides 96.
  // KS=16 -> grid 512 blocks = exactly 2 blocks/CU (reg-capped 2 waves/SIMD).
  static const int cands[] = {16, 12, 8, 6, 4, 3, 2, 1};
  const int NC = 8;

  // Workspace plan: [Wt | P].
  int KS = 0;
  for (int i = 0; i < NC; ++i)
    if (WT_BYTES + (size_t)cands[i] * slice <= ws_size) { KS = cands[i]; break; }

  uint4* Wt = (uint4*)d_ws;
  const int nwt = NK32 * 128 * 4;

  prep<<<(nwt + 255) / 256, 256, 0, stream>>>(Wf, Wt);

  if (KS > 0) {
    float* P = (float*)((char*)d_ws + WT_BYTES);
    bilinear_main<<<dim3(KS, 32), 256, 0, stream>>>(
        b1f, b2f, (const char*)Wt, bbf, P, nullptr, KTOT / KS);
    launch_reduce(KS, P, bbf, out, stream);
  } else {
    // Minimal-workspace fallback: single slice, direct f32 output.
    bilinear_main<<<dim3(1, 32), 256, 0, stream>>>(
        b1f, b2f, (const char*)Wt, bbf, nullptr, out, KTOT);
  }
}

// Round 9
// 155.481 us; speedup vs baseline: 1.3776x; 1.3776x over previous
//
#include <hip/hip_runtime.h>
#include <hip/hip_bf16.h>
#include <stdint.h>

// Problem constants
#define NROWS 4096
#define NCLS  97
#define EMB   768
#define KTOT  49152                 // EMB * 64
#define OUT_ELEMS (NROWS * NCLS)    // 397312
#define E_ELEMS  (NROWS * EMB)      // 3,145,728
#define NK32  (KTOT / 32)           // 1536 k-chunks of 32
#define WT_BYTES ((size_t)NK32 * 128 * 64)   // 12,582,912 (Wt: [kc][c<128][32] f16)

typedef __attribute__((ext_vector_type(4)))  float floatx4;
typedef _Float16 f16x2 __attribute__((ext_vector_type(2)));
typedef _Float16 f16x8 __attribute__((ext_vector_type(8)));

// Pack 8 f32 -> 8 f16 (RNE via scalar casts) as a uint4.
__device__ __forceinline__ uint4 cvt8h(float4 a, float4 b) {
  f16x8 v;
  v[0] = (_Float16)a.x; v[1] = (_Float16)a.y; v[2] = (_Float16)a.z; v[3] = (_Float16)a.w;
  v[4] = (_Float16)b.x; v[5] = (_Float16)b.y; v[6] = (_Float16)b.z; v[7] = (_Float16)b.w;
  return __builtin_bit_cast(uint4, v);
}

// Raw 16B global load the compiler cannot sink/merge/re-wait: asm volatile
// order is preserved among asm statements, and the dest is a real register.
template<int OFF>
__device__ __forceinline__ uint4 gl16(const char* p) {
  uint4 d;
  asm volatile("global_load_dwordx4 %0, %1, off offset:%2"
               : "=v"(d) : "v"(p), "i"(OFF));
  return d;
}

// Counted wait: N = number of loads issued in the current slot. Leaves the
// newest N outstanding; everything older (the consumed window) is drained.
// sched_barrier(0) pins all following MFMA/VALU after the wait (rule #18).
#define WAITVM(N) do {                                                       \
    asm volatile("s_waitcnt vmcnt(" #N ")" ::: "memory");                    \
    __builtin_amdgcn_sched_barrier(0);                                       \
  } while (0)

// Prep: build Wt (W transposed into MFMA B-fragment order, f16, classes
// padded to 128 with zeros). b1/b2 are consumed in f32 directly.
// Wt 16B-chunk t: eo=t&3 (8-elem octet), c=(t>>2)&127, kc=t>>9:
//   Wt byte addr = kc*8192 + c*64 + eo*16  <-> W[c][kc*32 + eo*8 .. +7]
__global__ void prep(const float* __restrict__ W, uint4* __restrict__ wt)
{
  const int nwt = NK32 * 128 * 4;      // 786,432
  int t = blockIdx.x * blockDim.x + threadIdx.x;
  if (t >= nwt) return;
  int eo = t & 3;
  int c  = (t >> 2) & 127;
  int kc = t >> 9;
  uint4 v = uint4{0u, 0u, 0u, 0u};
  if (c < NCLS) {
    const float4* p = (const float4*)(W + (size_t)c * KTOT + kc * 32 + eo * 8);
    v = cvt8h(p[0], p[1]);
  }
  wt[t] = v;
}

// Fused on-the-fly-A GEMM, R18: counted-vmcnt register pipeline (T4).
// Diagnosis ledger: R10-R15 MfmaUtil pinned 24-30%; R15 VGPR=112 proves the
// compiler silently un-did the source-level ping-pong (m133) and drains
// vmcnt to ~0 per window -> one exposed L2 latency per window (~1000+ cyc
// dead per window-pair). R17 (LDS+syncthreads) made it worse: 8-way ds_read
// bank conflict (2.75M) + double vmcnt(0) drain per window (T4 anti-pattern).
// R18: NO LDS, NO barriers. All hot-loop VMEM is asm volatile:
//   slot i: [s==3: issue 4 b1 loads (group-parity dbuf)] -> issue 8 Wt loads
//   (window i+1, reg ping-pong wfA/wfB) -> s_waitcnt vmcnt(8|12) (= loads
//   issued THIS slot; drains window i's loads, keeps i+1 in flight) ->
//   sched_barrier(0) -> f16 A-build + 28 MFMA.
// Invariant: leaves-newest-N (N = this slot's issues) => all earlier slots'
// loads complete. Uniform 8 Wt loads/wave (ct3 zero-pad loaded, MFMA still
// skipped for chalf==1). b2 reload (<=1/block) stays compiler-scheduled.
// MFMA floor: 96 windows/SIMD x 543 cyc = 21.7 us.
// MFMA 16x16x32 verified triple:
//   A: lane l holds A[m=l&15][k=(l>>4)*8+j]; B: W[c=l&15][k=(l>>4)*8+j]
//   D: lane l, reg r: col(c)=l&15, row(n)=(l>>4)*4+r
// Grid (KS, 32): x = k-slice (XCD co-location when gridDim.x%8==0),
// y = 128-row tile. rt=4 kept (each Wt fragment feeds 4 MFMAs).
__global__ __launch_bounds__(256, 2)
void bilinear_main(const float* __restrict__ b1f,
                   const float* __restrict__ b2f,
                   const char* __restrict__ Wt,
                   const float* __restrict__ biasg,
                   float* __restrict__ P,
                   float* __restrict__ outd,
                   int klen)
{
  const int tid  = threadIdx.x;
  const int w    = tid >> 6;
  const int l    = tid & 63;
  const int l15  = l & 15;
  const int quad = l >> 4;
  const int mhalf = w & 1;
  const int chalf = w >> 1;
  const bool cfull = (chalf == 0);   // chalf=1 waves skip ct==3 MFMA (pad)
  const int bm = blockIdx.y;
  const int k0 = blockIdx.x * klen;

  int nrow[4];
#pragma unroll
  for (int rt = 0; rt < 4; ++rt) nrow[rt] = bm * 128 + mhalf * 64 + rt * 16 + l15;

  // Lane-fixed Wt base for this block's k-range.
  const char* wtl = Wt + (size_t)(k0 >> 5) * 8192
                       + (chalf * 64 + l15) * 64 + quad * 16;

  floatx4 acc[4][4];
#pragma unroll
  for (int rt = 0; rt < 4; ++rt)
#pragma unroll
    for (int ct = 0; ct < 4; ++ct)
      acc[rt][ct] = floatx4{0.f, 0.f, 0.f, 0.f};

  // f16-pair cache of b2[nrow[rt], kb*64 + kh*32 + quad*8 + 2j,2j+1].
  f16x2 b2h[4][2][4];
  uint4 wfA[2][4], wfB[2][4];   // Wt fragment ping-pong [kh][ct]
  uint4 b1X[4], b1Y[4];         // b1 group-parity double buffer (f32 bits)

#define LOADB2(kbv) do {                                                      \
    _Pragma("unroll")                                                         \
    for (int rt_ = 0; rt_ < 4; ++rt_)                                         \
      _Pragma("unroll")                                                       \
      for (int kh_ = 0; kh_ < 2; ++kh_) {                                     \
        const float* p_ = b2f + (size_t)nrow[rt_] * EMB + (kbv) * 64 +        \
                          kh_ * 32 + quad * 8;                                \
        float4 v0_ = ((const float4*)p_)[0];                                  \
        float4 v1_ = ((const float4*)p_)[1];                                  \
        b2h[rt_][kh_][0][0] = (_Float16)v0_.x; b2h[rt_][kh_][0][1] = (_Float16)v0_.y; \
        b2h[rt_][kh_][1][0] = (_Float16)v0_.z; b2h[rt_][kh_][1][1] = (_Float16)v0_.w; \
        b2h[rt_][kh_][2][0] = (_Float16)v1_.x; b2h[rt_][kh_][2][1] = (_Float16)v1_.y; \
        b2h[rt_][kh_][3][0] = (_Float16)v1_.z; b2h[rt_][kh_][3][1] = (_Float16)v1_.w; \
      }                                                                       \
  } while (0)

#define ISSUE_WF(buf, iwv) do {                                               \
    const char* pw_  = wtl + (size_t)(iwv) * 16384;                           \
    const char* pw1_ = pw_ + 8192;                                            \
    buf[0][0] = gl16<0>(pw_);     buf[0][1] = gl16<1024>(pw_);                \
    buf[0][2] = gl16<2048>(pw_);  buf[0][3] = gl16<3072>(pw_);                \
    buf[1][0] = gl16<0>(pw1_);    buf[1][1] = gl16<1024>(pw1_);               \
    buf[1][2] = gl16<2048>(pw1_); buf[1][3] = gl16<3072>(pw1_);               \
  } while (0)

#define ISSUE_B1(buf, kapv) do {                                              \
    _Pragma("unroll")                                                         \
    for (int rt_ = 0; rt_ < 4; ++rt_)                                         \
      buf[rt_] = gl16<0>((const char*)(b1f + (size_t)nrow[rt_] * EMB +        \
                         ((kapv) >> 12) * 64 + (((kapv) >> 6) & 63)));        \
  } while (0)

#define COMPUTE(BUF, BU, S) do {                                              \
    f16x2 sv_[4];                                                             \
    _Pragma("unroll")                                                         \
    for (int rt_ = 0; rt_ < 4; ++rt_) {                                       \
      float4 bv_ = __builtin_bit_cast(float4, BU[rt_]);                       \
      _Float16 h_ = (_Float16)((&bv_.x)[S]);                                  \
      sv_[rt_][0] = h_; sv_[rt_][1] = h_;                                     \
    }                                                                         \
    _Pragma("unroll")                                                         \
    for (int kh_ = 0; kh_ < 2; ++kh_)                                         \
      _Pragma("unroll")                                                       \
      for (int rt_ = 0; rt_ < 4; ++rt_) {                                     \
        f16x2 p0_ = sv_[rt_] * b2h[rt_][kh_][0];                              \
        f16x2 p1_ = sv_[rt_] * b2h[rt_][kh_][1];                              \
        f16x2 p2_ = sv_[rt_] * b2h[rt_][kh_][2];                              \
        f16x2 p3_ = sv_[rt_] * b2h[rt_][kh_][3];                              \
        uint4 au_;                                                            \
        au_.x = __builtin_bit_cast(uint32_t, p0_);                            \
        au_.y = __builtin_bit_cast(uint32_t, p1_);                            \
        au_.z = __builtin_bit_cast(uint32_t, p2_);                            \
        au_.w = __builtin_bit_cast(uint32_t, p3_);                            \
        f16x8 af_ = __builtin_bit_cast(f16x8, au_);                           \
        _Pragma("unroll")                                                     \
        for (int ct_ = 0; ct_ < 4; ++ct_)                                     \
          if (ct_ < 3 || cfull)                                               \
            acc[rt_][ct_] = __builtin_amdgcn_mfma_f32_16x16x32_f16(           \
                af_, __builtin_bit_cast(f16x8, BUF[kh_][ct_]),                \
                acc[rt_][ct_], 0, 0, 0);                                      \
      }                                                                       \
  } while (0)

// One group = 4 windows (256 k, one b1 float4). BU = this group's b1 regs
// (valid), BP = buffer to prefetch the NEXT group's b1 into (at s==3).
// Slot order: [b1?] -> 8 wf loads -> WAITVM(this slot's issue count) ->
// sched_barrier -> compute. Window parity = s&1 (gp*4 even).
#define GROUP_BODY(gp, BU, BP) do {                                           \
    const int kap_g_ = k0 + (gp) * 256;                                       \
    const int kb_ = kap_g_ >> 12;                                             \
    if (kb_ != cur_kb) { cur_kb = kb_; LOADB2(kb_); }                         \
    _Pragma("unroll")                                                         \
    for (int s = 0; s < 4; ++s) {                                             \
      const int iw_ = (gp) * 4 + s;                                           \
      if (s == 3) {                                                           \
        int hg_ = ((gp) + 1 < ngrp) ? (gp) + 1 : (gp);                        \
        int kap_h_ = k0 + hg_ * 256;                                          \
        ISSUE_B1(BP, kap_h_);                                                 \
      }                                                                       \
      int ipf_ = (iw_ + 1 < nwin) ? iw_ + 1 : nwin - 1;                       \
      if ((s & 1) == 0) {                                                     \
        ISSUE_WF(wfB, ipf_);                                                  \
        WAITVM(8);                                                            \
        COMPUTE(wfA, BU, s);                                                  \
      } else if (s == 1) {                                                    \
        ISSUE_WF(wfA, ipf_);                                                  \
        WAITVM(8);                                                            \
        COMPUTE(wfB, BU, s);                                                  \
      } else {  /* s == 3: 4 b1 + 8 wf issued this slot */                    \
        ISSUE_WF(wfA, ipf_);                                                  \
        WAITVM(12);                                                           \
        COMPUTE(wfB, BU, s);                                                  \
      }                                                                       \
    }                                                                         \
  } while (0)

  const int nwin = klen >> 6;         // 64-k windows
  const int ngrp = nwin >> 2;         // groups of 4 windows; even for all KS

  // ---- prologue: b2 + group-0 b1 via normal loads; window 0 via asm ----
  int cur_kb = k0 >> 12;
  LOADB2(cur_kb);
#pragma unroll
  for (int rt = 0; rt < 4; ++rt)
    b1X[rt] = *(const uint4*)(b1f + (size_t)nrow[rt] * EMB +
                              cur_kb * 64 + ((k0 >> 6) & 63));
  ISSUE_WF(wfA, 0);

  for (int g2 = 0; g2 < ngrp; g2 += 2) {
    GROUP_BODY(g2,     b1X, b1Y);
    GROUP_BODY(g2 + 1, b1Y, b1X);
  }
#undef GROUP_BODY
#undef COMPUTE
#undef ISSUE_B1
#undef ISSUE_WF
#undef LOADB2

  // Epilogue. D: col(c)=l15, row(n)=quad*4+r within each 16x16 tile.
  if (P) {
    float* Pb = P + (size_t)blockIdx.x * OUT_ELEMS;   // slice = blockIdx.x
#pragma unroll
    for (int rt = 0; rt < 4; ++rt)
#pragma unroll
      for (int ct = 0; ct < 4; ++ct) {
        const int c = chalf * 64 + ct * 16 + l15;
        if (c < NCLS) {
#pragma unroll
          for (int r = 0; r < 4; ++r) {
            const int row = bm * 128 + mhalf * 64 + rt * 16 + quad * 4 + r;
            Pb[(size_t)row * NCLS + c] = acc[rt][ct][r];
          }
        }
      }
  } else {
#pragma unroll
    for (int rt = 0; rt < 4; ++rt)
#pragma unroll
      for (int ct = 0; ct < 4; ++ct) {
        const int c = chalf * 64 + ct * 16 + l15;
        if (c < NCLS) {
          const float bv = biasg[c];
#pragma unroll
          for (int r = 0; r < 4; ++r) {
            const int row = bm * 128 + mhalf * 64 + rt * 16 + quad * 4 + r;
            outd[(size_t)row * NCLS + c] = acc[rt][ct][r] + bv;
          }
        }
      }
  }
}

// Sum KS partial slices + f32 bias -> f32 output. float4-vectorized.
// KS templated so the accumulation loop fully unrolls (runtime bound left a
// dependent load->add chain, one L2 latency per slice).
template<int KSC>
__global__ void reduce_bias_t(const float* __restrict__ P,
                              const float* __restrict__ biasg,
                              float* __restrict__ out)
{
  int i = blockIdx.x * blockDim.x + threadIdx.x;
  const int n4 = OUT_ELEMS / 4;           // 99328
  if (i >= n4) return;
  int c0 = (i * 4) % NCLS;
  int c1 = c0 + 1 == NCLS ? 0 : c0 + 1;
  int c2 = c1 + 1 == NCLS ? 0 : c1 + 1;
  int c3 = c2 + 1 == NCLS ? 0 : c2 + 1;
  float4 s;
  s.x = biasg[c0]; s.y = biasg[c1]; s.z = biasg[c2]; s.w = biasg[c3];
  const float4* P4 = (const float4*)P;
#pragma unroll
  for (int t = 0; t < KSC; ++t) {
    float4 v = P4[(size_t)t * n4 + i];
    s.x += v.x; s.y += v.y; s.z += v.z; s.w += v.w;
  }
  ((float4*)out)[i] = s;
}

static void launch_reduce(int KS, const float* P, const float* bb, float* out,
                          hipStream_t stream) {
  const int nb = (OUT_ELEMS / 4 + 255) / 256;
  switch (KS) {
    case 16: reduce_bias_t<16><<<nb, 256, 0, stream>>>(P, bb, out); break;
    case 12: reduce_bias_t<12><<<nb, 256, 0, stream>>>(P, bb, out); break;
    case 8:  reduce_bias_t<8><<<nb, 256, 0, stream>>>(P, bb, out);  break;
    case 6:  reduce_bias_t<6><<<nb, 256, 0, stream>>>(P, bb, out);  break;
    case 4:  reduce_bias_t<4><<<nb, 256, 0, stream>>>(P, bb, out);  break;
    case 3:  reduce_bias_t<3><<<nb, 256, 0, stream>>>(P, bb, out);  break;
    case 2:  reduce_bias_t<2><<<nb, 256, 0, stream>>>(P, bb, out);  break;
    default: reduce_bias_t<1><<<nb, 256, 0, stream>>>(P, bb, out);  break;
  }
}

extern "C" void kernel_launch(void* const* d_in, const int* in_sizes, int n_in,
                              void* d_out, int out_size, void* d_ws, size_t ws_size,
                              hipStream_t stream) {
  const float* b1f = (const float*)d_in[0];   // [4096,768] f32
  const float* b2f = (const float*)d_in[1];   // [4096,768] f32
  const float* Wf  = (const float*)d_in[2];   // [97, 49152] f32
  const float* bbf = (const float*)d_in[3];   // [97] f32
  float* out = (float*)d_out;

  const size_t slice = (size_t)OUT_ELEMS * 4;     // 1,589,248
  // klen = KTOT/KS must be a multiple of 512 -> KS divides 96.
  // KS=16 -> grid 512 blocks = exactly 2 blocks/CU (reg-capped 2 waves/SIMD).
  static const int cands[] = {16, 12, 8, 6, 4, 3, 2, 1};
  const int NC = 8;

  // Workspace plan: [Wt | P].
  int KS = 0;
  for (int i = 0; i < NC; ++i)
    if (WT_BYTES + (size_t)cands[i] * slice <= ws_size) { KS = cands[i]; break; }

  uint4* Wt = (uint4*)d_ws;
  const int nwt = NK32 * 128 * 4;

  prep<<<(nwt + 255) / 256, 256, 0, stream>>>(Wf, Wt);

  if (KS > 0) {
    float* P = (float*)((char*)d_ws + WT_BYTES);
    bilinear_main<<<dim3(KS, 32), 256, 0, stream>>>(
        b1f, b2f, (const char*)Wt, bbf, P, nullptr, KTOT / KS);
    launch_reduce(KS, P, bbf, out, stream);
  } else {
    // Minimal-workspace fallback: single slice, direct f32 output.
    bilinear_main<<<dim3(1, 32), 256, 0, stream>>>(
        b1f, b2f, (const char*)Wt, bbf, nullptr, out, KTOT);
  }
}